// Round 4
// baseline (332.525 us; speedup 1.0000x reference)
//
#include <hip/hip_runtime.h>
#include <hip/hip_bf16.h>
#include <math.h>

#define BINS 100
#define NBINS2 (BINS * BINS)
#define NHIST 8                 // split global histograms to cut atomic contention
#define GRID_SIMHIST 2048       // rows/block <= 544 < 65535: 16-bit LDS counters safe

// ws layout (unsigned words):
//   ws[0] : monotone-encoded min of distances
//   ws[1] : monotone-encoded max of distances
//   ws[16 + h*NBINS2 + i], h=0..7 : 8 partial joint histograms (uint)

static __device__ __forceinline__ unsigned enc_f32(float f) {
    unsigned u = __float_as_uint(f);
    return (u & 0x80000000u) ? ~u : (u | 0x80000000u);
}
static __device__ __forceinline__ float dec_f32(unsigned e) {
    unsigned u = (e & 0x80000000u) ? (e & 0x7FFFFFFFu) : ~e;
    return __uint_as_float(u);
}

__global__ void k_init(unsigned* ws) {
    int i = blockIdx.x * blockDim.x + threadIdx.x;
    if (i == 0) { ws[0] = 0xFFFFFFFFu; ws[1] = 0u; }
    if (i < NHIST * NBINS2) ws[16 + i] = 0u;
}

__global__ __launch_bounds__(256) void k_minmax(const float* __restrict__ d, int n, unsigned* ws) {
    int tid = blockIdx.x * blockDim.x + threadIdx.x;
    int stride = gridDim.x * blockDim.x;
    float mn = INFINITY, mx = -INFINITY;
    int n4 = n >> 2;
    for (int i = tid; i < n4; i += stride) {
        float4 v = ((const float4*)d)[i];
        mn = fminf(mn, fminf(fminf(v.x, v.y), fminf(v.z, v.w)));
        mx = fmaxf(mx, fmaxf(fmaxf(v.x, v.y), fmaxf(v.z, v.w)));
    }
    int rem = n & 3;
    if (tid < rem) {
        float v = d[(n4 << 2) + tid];
        mn = fminf(mn, v);
        mx = fmaxf(mx, v);
    }
    #pragma unroll
    for (int off = 32; off; off >>= 1) {
        mn = fminf(mn, __shfl_xor(mn, off));
        mx = fmaxf(mx, __shfl_xor(mx, off));
    }
    if ((threadIdx.x & 63) == 0) {
        atomicMin(&ws[0], enc_f32(mn));
        atomicMax(&ws[1], enc_f32(mx));
    }
}

// searchsorted(edges, x, 'right') - 1: largest i with e[i] <= x < e[i+1].
static __device__ __forceinline__ int bin_fix(double x, const double* __restrict__ e, int guess) {
    int i = guess;
    if (i < 0) i = 0; else if (i > BINS - 1) i = BINS - 1;
    while (i >= 0 && x < e[i]) --i;           // -> -1 if x < e[0]
    while (i < BINS && x >= e[i + 1]) ++i;    // -> BINS if x >= e[BINS]
    return i;
}

// Compute sims for one 8-row group; s==0 lanes deposit sim into vsim[k*8+r].
static __device__ __forceinline__ void group_sim(
    const float4* __restrict__ e1, const float4* __restrict__ e2,
    int g, int r, int s, int k, volatile float* vsim)
{
    size_t base = (size_t)g * 256 + (size_t)(r * 32 + s);
    float4 a0 = e1[base], a1 = e1[base + 8], a2 = e1[base + 16], a3 = e1[base + 24];
    float4 b0 = e2[base], b1 = e2[base + 8], b2 = e2[base + 16], b3 = e2[base + 24];

    float dot = a0.x*b0.x + a0.y*b0.y + a0.z*b0.z + a0.w*b0.w
              + a1.x*b1.x + a1.y*b1.y + a1.z*b1.z + a1.w*b1.w
              + a2.x*b2.x + a2.y*b2.y + a2.z*b2.z + a2.w*b2.w
              + a3.x*b3.x + a3.y*b3.y + a3.z*b3.z + a3.w*b3.w;
    float n1  = a0.x*a0.x + a0.y*a0.y + a0.z*a0.z + a0.w*a0.w
              + a1.x*a1.x + a1.y*a1.y + a1.z*a1.z + a1.w*a1.w
              + a2.x*a2.x + a2.y*a2.y + a2.z*a2.z + a2.w*a2.w
              + a3.x*a3.x + a3.y*a3.y + a3.z*a3.z + a3.w*a3.w;
    float n2  = b0.x*b0.x + b0.y*b0.y + b0.z*b0.z + b0.w*b0.w
              + b1.x*b1.x + b1.y*b1.y + b1.z*b1.z + b1.w*b1.w
              + b2.x*b2.x + b2.y*b2.y + b2.z*b2.z + b2.w*b2.w
              + b3.x*b3.x + b3.y*b3.y + b3.z*b3.z + b3.w*b3.w;

    dot += __shfl_xor(dot, 1); n1 += __shfl_xor(n1, 1); n2 += __shfl_xor(n2, 1);
    dot += __shfl_xor(dot, 2); n1 += __shfl_xor(n1, 2); n2 += __shfl_xor(n2, 2);
    dot += __shfl_xor(dot, 4); n1 += __shfl_xor(n1, 4); n2 += __shfl_xor(n2, 4);

    if (s == 0) {
        float sim = dot / (fmaxf(sqrtf(n1), 1e-12f) * fmaxf(sqrtf(n2), 1e-12f));
        vsim[k * 8 + r] = sim;
    }
}

// Each wave owns a CONTIGUOUS range of 8-row groups (64 KB sequential streams).
// Per macro-iter: 8 groups' sims staged in LDS, then all 64 lanes bin 64 rows
// at once (no divergence; coalesced dist loads). LDS hist packed 2 bins/uint.
__global__ __launch_bounds__(256) void k_simhist(
    const float* __restrict__ e1f, const float* __restrict__ e2f,
    const float* __restrict__ dist, int B, unsigned* ws)
{
    __shared__ unsigned s_hist[NBINS2 / 2];
    __shared__ double s_se[BINS + 1];
    __shared__ double s_de[BINS + 1];
    __shared__ double s_par[2];   // dist lo, dist inv_delta
    __shared__ float s_sim[4][64];

    for (int i = threadIdx.x; i < NBINS2 / 2; i += 256) s_hist[i] = 0u;
    if (threadIdx.x <= BINS) {
        int i = threadIdx.x;
        s_se[i] = (i == BINS) ? 1.0 : ((double)i * 0.02 - 1.0);
        double dmn = (double)dec_f32(ws[0]);
        double dmx = (double)dec_f32(ws[1]);
        double delta = (dmx - dmn) * 0.01;
        s_de[i] = (i == BINS) ? dmx : ((double)i * delta + dmn);
        if (i == 0) {
            s_par[0] = dmn;
            s_par[1] = (delta > 0.0) ? (1.0 / delta) : 0.0;
        }
    }
    __syncthreads();

    const float4* __restrict__ e1 = (const float4*)e1f;
    const float4* __restrict__ e2 = (const float4*)e2f;
    const int lane = threadIdx.x & 63;
    const int r = lane >> 3, s = lane & 7;
    const int wslot = threadIdx.x >> 6;
    const int w = blockIdx.x * 4 + wslot;
    const int nw = gridDim.x * 4;
    const int ngroups = B >> 3;
    const double dlo = s_par[0], dinv = s_par[1];
    volatile float* vsim = s_sim[wslot];

    // contiguous split of groups across waves
    int q = ngroups / nw, rem = ngroups % nw;
    int g0 = w * q + (w < rem ? w : rem);
    int g1 = g0 + q + (w < rem ? 1 : 0);

    for (int gb = g0; gb < g1; gb += 8) {
        int ng = g1 - gb; if (ng > 8) ng = 8;
        if (ng == 8) {
            #pragma unroll 2
            for (int k = 0; k < 8; ++k) group_sim(e1, e2, gb + k, r, s, k, vsim);
        } else {
            for (int k = 0; k < ng; ++k) group_sim(e1, e2, gb + k, r, s, k, vsim);
        }
        int nrows = ng << 3;
        if (lane < nrows) {
            int row = (gb << 3) + lane;
            double xs = (double)vsim[lane];
            int is = bin_fix(xs, s_se, (int)floor((xs + 1.0) * 50.0));
            double xd = (double)dist[row];
            int id = bin_fix(xd, s_de, (int)floor((xd - dlo) * dinv));
            if (is >= 0 && is < BINS && id >= 0 && id < BINS) {
                int bin = is * BINS + id;
                atomicAdd(&s_hist[bin >> 1], 1u << ((bin & 1) * 16));
            }
        }
    }

    // tail rows (B % 8 != 0): wave 0 of block 0
    int tail = B & 7;
    if (tail && blockIdx.x == 0 && threadIdx.x < 64) {
        for (int row = B - tail; row < B; ++row) {
            const float* p1 = e1f + (size_t)row * 128;
            const float* p2 = e2f + (size_t)row * 128;
            float a0 = p1[lane * 2], a1 = p1[lane * 2 + 1];
            float b0 = p2[lane * 2], b1 = p2[lane * 2 + 1];
            float dot = a0 * b0 + a1 * b1;
            float n1 = a0 * a0 + a1 * a1;
            float n2 = b0 * b0 + b1 * b1;
            #pragma unroll
            for (int off = 32; off; off >>= 1) {
                dot += __shfl_xor(dot, off);
                n1 += __shfl_xor(n1, off);
                n2 += __shfl_xor(n2, off);
            }
            if (lane == 0) {
                float sim = dot / (fmaxf(sqrtf(n1), 1e-12f) * fmaxf(sqrtf(n2), 1e-12f));
                double xs = (double)sim;
                int is = bin_fix(xs, s_se, (int)floor((xs + 1.0) * 50.0));
                double xd = (double)dist[row];
                int id = bin_fix(xd, s_de, (int)floor((xd - dlo) * dinv));
                if (is >= 0 && is < BINS && id >= 0 && id < BINS) {
                    int bin = is * BINS + id;
                    atomicAdd(&s_hist[bin >> 1], 1u << ((bin & 1) * 16));
                }
            }
        }
    }

    __syncthreads();
    unsigned* g = ws + 16 + (blockIdx.x & (NHIST - 1)) * NBINS2;
    for (int i = threadIdx.x; i < NBINS2 / 2; i += 256) {
        unsigned c = s_hist[i];
        if (c & 0xFFFFu)  atomicAdd(&g[2 * i],     c & 0xFFFFu);
        if (c >> 16)      atomicAdd(&g[2 * i + 1], c >> 16);
    }
}

__global__ __launch_bounds__(1024) void k_mi(const unsigned* __restrict__ counts, float* __restrict__ out) {
    __shared__ unsigned s_c[NBINS2];
    __shared__ double s_red[1024];
    __shared__ double s_lr[BINS], s_lc[BINS];
    const int tid = threadIdx.x;

    double t = 0.0;
    for (int i = tid; i < NBINS2; i += 1024) {
        unsigned c = 0;
        #pragma unroll
        for (int h = 0; h < NHIST; ++h) c += counts[h * NBINS2 + i];
        s_c[i] = c;
        t += (double)c;
    }
    s_red[tid] = t;
    __syncthreads();
    for (int off = 512; off; off >>= 1) {
        if (tid < off) s_red[tid] += s_red[tid + off];
        __syncthreads();
    }
    double tot = s_red[0];
    __syncthreads();

    if (tid < 8 * BINS) {
        int r = tid >> 3, s = tid & 7;
        double rs = 0.0, cs = 0.0;
        for (int j = s; j < BINS; j += 8) {
            rs += (double)s_c[r * BINS + j];
            cs += (double)s_c[j * BINS + r];
        }
        rs += __shfl_xor(rs, 1); cs += __shfl_xor(cs, 1);
        rs += __shfl_xor(rs, 2); cs += __shfl_xor(cs, 2);
        rs += __shfl_xor(rs, 4); cs += __shfl_xor(cs, 4);
        if (s == 0) {
            s_lr[r] = log(rs / tot + 1e-10);
            s_lc[r] = log(cs / tot + 1e-10);
        }
    }
    __syncthreads();

    double acc = 0.0;
    for (int i = tid; i < NBINS2; i += 1024) {
        unsigned c = s_c[i];
        if (c) {
            double p = (double)c / tot;
            acc += p * (log(p + 1e-10) - s_lr[i / BINS] - s_lc[i % BINS]);
        }
    }
    s_red[tid] = acc;
    __syncthreads();
    for (int off = 512; off; off >>= 1) {
        if (tid < off) s_red[tid] += s_red[tid + off];
        __syncthreads();
    }
    if (tid == 0) {
        double mi = s_red[0];
        double d1 = 0.0, d2 = 0.0;
        for (int i = 0; i < BINS; i++) { d1 -= s_lr[i]; d2 -= s_lc[i]; }
        out[0] = (float)(mi / fmin(d1, d2));
    }
}

extern "C" void kernel_launch(void* const* d_in, const int* in_sizes, int n_in,
                              void* d_out, int out_size, void* d_ws, size_t ws_size,
                              hipStream_t stream) {
    const float* e1 = (const float*)d_in[0];
    const float* e2 = (const float*)d_in[1];
    const float* dist = (const float*)d_in[2];
    const int B = in_sizes[2];
    unsigned* ws = (unsigned*)d_ws;

    k_init<<<(NHIST * NBINS2 + 255) / 256, 256, 0, stream>>>(ws);
    k_minmax<<<1024, 256, 0, stream>>>(dist, B, ws);
    k_simhist<<<GRID_SIMHIST, 256, 0, stream>>>(e1, e2, dist, B, ws);
    k_mi<<<1, 1024, 0, stream>>>(ws + 16, (float*)d_out);
}

// Round 5
// 296.416 us; speedup vs baseline: 1.1218x; 1.1218x over previous
//
#include <hip/hip_runtime.h>
#include <hip/hip_bf16.h>
#include <math.h>

#define BINS 100
#define NBINS2 (BINS * BINS)
#define NHIST 8                 // split global histograms to cut atomic contention
#define GRID_SIMHIST 2048       // rows/block <= 512 < 65535: 16-bit LDS counters safe

typedef float f32x4 __attribute__((ext_vector_type(4)));

static __device__ __forceinline__ f32x4 ntload(const f32x4* p) {
    return __builtin_nontemporal_load(p);
}

// ws layout (unsigned words):
//   ws[0] : monotone-encoded min of distances
//   ws[1] : monotone-encoded max of distances
//   ws[16 + h*NBINS2 + i], h=0..NHIST-1 : partial joint histograms (uint)

static __device__ __forceinline__ unsigned enc_f32(float f) {
    unsigned u = __float_as_uint(f);
    return (u & 0x80000000u) ? ~u : (u | 0x80000000u);
}
static __device__ __forceinline__ float dec_f32(unsigned e) {
    unsigned u = (e & 0x80000000u) ? (e & 0x7FFFFFFFu) : ~e;
    return __uint_as_float(u);
}

__global__ void k_init(unsigned* ws) {
    int i = blockIdx.x * blockDim.x + threadIdx.x;
    if (i == 0) { ws[0] = 0xFFFFFFFFu; ws[1] = 0u; }
    if (i < NHIST * NBINS2) ws[16 + i] = 0u;
}

__global__ __launch_bounds__(256) void k_minmax(const float* __restrict__ d, int n, unsigned* ws) {
    int tid = blockIdx.x * blockDim.x + threadIdx.x;
    int stride = gridDim.x * blockDim.x;
    float mn = INFINITY, mx = -INFINITY;
    int n4 = n >> 2;
    for (int i = tid; i < n4; i += stride) {
        float4 v = ((const float4*)d)[i];
        mn = fminf(mn, fminf(fminf(v.x, v.y), fminf(v.z, v.w)));
        mx = fmaxf(mx, fmaxf(fmaxf(v.x, v.y), fmaxf(v.z, v.w)));
    }
    int rem = n & 3;
    if (tid < rem) {
        float v = d[(n4 << 2) + tid];
        mn = fminf(mn, v);
        mx = fmaxf(mx, v);
    }
    #pragma unroll
    for (int off = 32; off; off >>= 1) {
        mn = fminf(mn, __shfl_xor(mn, off));
        mx = fmaxf(mx, __shfl_xor(mx, off));
    }
    if ((threadIdx.x & 63) == 0) {
        atomicMin(&ws[0], enc_f32(mn));
        atomicMax(&ws[1], enc_f32(mx));
    }
}

// searchsorted(edges, x, 'right') - 1: largest i with e[i] <= x < e[i+1].
static __device__ __forceinline__ int bin_fix(double x, const double* __restrict__ e, int guess) {
    int i = guess;
    if (i < 0) i = 0; else if (i > BINS - 1) i = BINS - 1;
    while (i >= 0 && x < e[i]) --i;           // -> -1 if x < e[0]
    while (i < BINS && x >= e[i + 1]) ++i;    // -> BINS if x >= e[BINS]
    return i;
}

// 2 groups x 8 rows per wave-iteration: lane = 8*r + s; within a group the lane
// covers row (g*8+r), float4 columns s+8k, k=0..3. 16 independent nt dwordx4
// loads in flight per lane-iter; wave moves 16 KB per iteration.
__global__ __launch_bounds__(256) void k_simhist(
    const float* __restrict__ e1f, const float* __restrict__ e2f,
    const float* __restrict__ dist, int B, unsigned* ws)
{
    __shared__ unsigned s_hist[NBINS2 / 2];
    __shared__ double s_se[BINS + 1];
    __shared__ double s_de[BINS + 1];
    __shared__ double s_par[2];   // dist lo, dist inv_delta

    for (int i = threadIdx.x; i < NBINS2 / 2; i += 256) s_hist[i] = 0u;
    if (threadIdx.x <= BINS) {
        int i = threadIdx.x;
        s_se[i] = (i == BINS) ? 1.0 : ((double)i * 0.02 - 1.0);
        double dmn = (double)dec_f32(ws[0]);
        double dmx = (double)dec_f32(ws[1]);
        double delta = (dmx - dmn) * 0.01;
        s_de[i] = (i == BINS) ? dmx : ((double)i * delta + dmn);
        if (i == 0) {
            s_par[0] = dmn;
            s_par[1] = (delta > 0.0) ? (1.0 / delta) : 0.0;
        }
    }
    __syncthreads();

    const f32x4* __restrict__ e1 = (const f32x4*)e1f;
    const f32x4* __restrict__ e2 = (const f32x4*)e2f;
    const int lane = threadIdx.x & 63;
    const int r = lane >> 3, s = lane & 7;
    const int wid = (blockIdx.x * 256 + threadIdx.x) >> 6;
    const int nw = (gridDim.x * 256) >> 6;
    const int ngroups = B >> 3;
    const int ngpair = ngroups & ~1;
    const double dlo = s_par[0], dinv = s_par[1];

    for (int g = wid * 2; g < ngpair; g += nw * 2) {
        size_t baseA = (size_t)g * 256 + (size_t)(r * 32 + s);
        size_t baseB = baseA + 256;
        // 16 independent nontemporal loads per matrix pair (8 KB x2 per wave)
        f32x4 a0 = ntload(e1 + baseA), a1 = ntload(e1 + baseA + 8),
              a2 = ntload(e1 + baseA + 16), a3 = ntload(e1 + baseA + 24);
        f32x4 c0 = ntload(e1 + baseB), c1 = ntload(e1 + baseB + 8),
              c2 = ntload(e1 + baseB + 16), c3 = ntload(e1 + baseB + 24);
        f32x4 b0 = ntload(e2 + baseA), b1 = ntload(e2 + baseA + 8),
              b2 = ntload(e2 + baseA + 16), b3 = ntload(e2 + baseA + 24);
        f32x4 d0 = ntload(e2 + baseB), d1 = ntload(e2 + baseB + 8),
              d2 = ntload(e2 + baseB + 16), d3 = ntload(e2 + baseB + 24);

        float dotA = a0.x*b0.x + a0.y*b0.y + a0.z*b0.z + a0.w*b0.w
                   + a1.x*b1.x + a1.y*b1.y + a1.z*b1.z + a1.w*b1.w
                   + a2.x*b2.x + a2.y*b2.y + a2.z*b2.z + a2.w*b2.w
                   + a3.x*b3.x + a3.y*b3.y + a3.z*b3.z + a3.w*b3.w;
        float n1A  = a0.x*a0.x + a0.y*a0.y + a0.z*a0.z + a0.w*a0.w
                   + a1.x*a1.x + a1.y*a1.y + a1.z*a1.z + a1.w*a1.w
                   + a2.x*a2.x + a2.y*a2.y + a2.z*a2.z + a2.w*a2.w
                   + a3.x*a3.x + a3.y*a3.y + a3.z*a3.z + a3.w*a3.w;
        float n2A  = b0.x*b0.x + b0.y*b0.y + b0.z*b0.z + b0.w*b0.w
                   + b1.x*b1.x + b1.y*b1.y + b1.z*b1.z + b1.w*b1.w
                   + b2.x*b2.x + b2.y*b2.y + b2.z*b2.z + b2.w*b2.w
                   + b3.x*b3.x + b3.y*b3.y + b3.z*b3.z + b3.w*b3.w;

        float dotB = c0.x*d0.x + c0.y*d0.y + c0.z*d0.z + c0.w*d0.w
                   + c1.x*d1.x + c1.y*d1.y + c1.z*d1.z + c1.w*d1.w
                   + c2.x*d2.x + c2.y*d2.y + c2.z*d2.z + c2.w*d2.w
                   + c3.x*d3.x + c3.y*d3.y + c3.z*d3.z + c3.w*d3.w;
        float n1B  = c0.x*c0.x + c0.y*c0.y + c0.z*c0.z + c0.w*c0.w
                   + c1.x*c1.x + c1.y*c1.y + c1.z*c1.z + c1.w*c1.w
                   + c2.x*c2.x + c2.y*c2.y + c2.z*c2.z + c2.w*c2.w
                   + c3.x*c3.x + c3.y*c3.y + c3.z*c3.z + c3.w*c3.w;
        float n2B  = d0.x*d0.x + d0.y*d0.y + d0.z*d0.z + d0.w*d0.w
                   + d1.x*d1.x + d1.y*d1.y + d1.z*d1.z + d1.w*d1.w
                   + d2.x*d2.x + d2.y*d2.y + d2.z*d2.z + d2.w*d2.w
                   + d3.x*d3.x + d3.y*d3.y + d3.z*d3.z + d3.w*d3.w;

        dotA += __shfl_xor(dotA, 1); n1A += __shfl_xor(n1A, 1); n2A += __shfl_xor(n2A, 1);
        dotA += __shfl_xor(dotA, 2); n1A += __shfl_xor(n1A, 2); n2A += __shfl_xor(n2A, 2);
        dotA += __shfl_xor(dotA, 4); n1A += __shfl_xor(n1A, 4); n2A += __shfl_xor(n2A, 4);
        dotB += __shfl_xor(dotB, 1); n1B += __shfl_xor(n1B, 1); n2B += __shfl_xor(n2B, 1);
        dotB += __shfl_xor(dotB, 2); n1B += __shfl_xor(n1B, 2); n2B += __shfl_xor(n2B, 2);
        dotB += __shfl_xor(dotB, 4); n1B += __shfl_xor(n1B, 4); n2B += __shfl_xor(n2B, 4);

        if (s == 0) {
            {
                int row = (g << 3) + r;
                float sim = dotA / (fmaxf(sqrtf(n1A), 1e-12f) * fmaxf(sqrtf(n2A), 1e-12f));
                double xs = (double)sim;
                int is = bin_fix(xs, s_se, (int)floor((xs + 1.0) * 50.0));
                double xd = (double)__builtin_nontemporal_load(dist + row);
                int id = bin_fix(xd, s_de, (int)floor((xd - dlo) * dinv));
                if (is >= 0 && is < BINS && id >= 0 && id < BINS) {
                    int bin = is * BINS + id;
                    atomicAdd(&s_hist[bin >> 1], 1u << ((bin & 1) * 16));
                }
            }
            {
                int row = ((g + 1) << 3) + r;
                float sim = dotB / (fmaxf(sqrtf(n1B), 1e-12f) * fmaxf(sqrtf(n2B), 1e-12f));
                double xs = (double)sim;
                int is = bin_fix(xs, s_se, (int)floor((xs + 1.0) * 50.0));
                double xd = (double)__builtin_nontemporal_load(dist + row);
                int id = bin_fix(xd, s_de, (int)floor((xd - dlo) * dinv));
                if (is >= 0 && is < BINS && id >= 0 && id < BINS) {
                    int bin = is * BINS + id;
                    atomicAdd(&s_hist[bin >> 1], 1u << ((bin & 1) * 16));
                }
            }
        }
    }

    // tail rows (odd last group and/or B % 8): block 0, wave 0, serial per row
    int tail_start = ngpair << 3;
    if (tail_start < B && blockIdx.x == 0 && threadIdx.x < 64) {
        for (int row = tail_start; row < B; ++row) {
            const float* p1 = e1f + (size_t)row * 128;
            const float* p2 = e2f + (size_t)row * 128;
            float a0 = p1[lane * 2], a1 = p1[lane * 2 + 1];
            float b0 = p2[lane * 2], b1 = p2[lane * 2 + 1];
            float dot = a0 * b0 + a1 * b1;
            float n1 = a0 * a0 + a1 * a1;
            float n2 = b0 * b0 + b1 * b1;
            #pragma unroll
            for (int off = 32; off; off >>= 1) {
                dot += __shfl_xor(dot, off);
                n1 += __shfl_xor(n1, off);
                n2 += __shfl_xor(n2, off);
            }
            if (lane == 0) {
                float sim = dot / (fmaxf(sqrtf(n1), 1e-12f) * fmaxf(sqrtf(n2), 1e-12f));
                double xs = (double)sim;
                int is = bin_fix(xs, s_se, (int)floor((xs + 1.0) * 50.0));
                double xd = (double)dist[row];
                int id = bin_fix(xd, s_de, (int)floor((xd - dlo) * dinv));
                if (is >= 0 && is < BINS && id >= 0 && id < BINS) {
                    int bin = is * BINS + id;
                    atomicAdd(&s_hist[bin >> 1], 1u << ((bin & 1) * 16));
                }
            }
        }
    }

    __syncthreads();
    unsigned* g = ws + 16 + (blockIdx.x & (NHIST - 1)) * NBINS2;
    for (int i = threadIdx.x; i < NBINS2 / 2; i += 256) {
        unsigned c = s_hist[i];
        if (c & 0xFFFFu)  atomicAdd(&g[2 * i],     c & 0xFFFFu);
        if (c >> 16)      atomicAdd(&g[2 * i + 1], c >> 16);
    }
}

__global__ __launch_bounds__(1024) void k_mi(const unsigned* __restrict__ counts, float* __restrict__ out) {
    __shared__ unsigned s_c[NBINS2];
    __shared__ double s_red[1024];
    __shared__ double s_lr[BINS], s_lc[BINS];
    const int tid = threadIdx.x;

    double t = 0.0;
    for (int i = tid; i < NBINS2; i += 1024) {
        unsigned c = 0;
        #pragma unroll
        for (int h = 0; h < NHIST; ++h) c += counts[h * NBINS2 + i];
        s_c[i] = c;
        t += (double)c;
    }
    s_red[tid] = t;
    __syncthreads();
    for (int off = 512; off; off >>= 1) {
        if (tid < off) s_red[tid] += s_red[tid + off];
        __syncthreads();
    }
    double tot = s_red[0];
    __syncthreads();

    if (tid < 8 * BINS) {
        int r = tid >> 3, s = tid & 7;
        double rs = 0.0, cs = 0.0;
        for (int j = s; j < BINS; j += 8) {
            rs += (double)s_c[r * BINS + j];
            cs += (double)s_c[j * BINS + r];
        }
        rs += __shfl_xor(rs, 1); cs += __shfl_xor(cs, 1);
        rs += __shfl_xor(rs, 2); cs += __shfl_xor(cs, 2);
        rs += __shfl_xor(rs, 4); cs += __shfl_xor(cs, 4);
        if (s == 0) {
            s_lr[r] = log(rs / tot + 1e-10);
            s_lc[r] = log(cs / tot + 1e-10);
        }
    }
    __syncthreads();

    double acc = 0.0;
    for (int i = tid; i < NBINS2; i += 1024) {
        unsigned c = s_c[i];
        if (c) {
            double p = (double)c / tot;
            acc += p * (log(p + 1e-10) - s_lr[i / BINS] - s_lc[i % BINS]);
        }
    }
    s_red[tid] = acc;
    __syncthreads();
    for (int off = 512; off; off >>= 1) {
        if (tid < off) s_red[tid] += s_red[tid + off];
        __syncthreads();
    }
    if (tid == 0) {
        double mi = s_red[0];
        double d1 = 0.0, d2 = 0.0;
        for (int i = 0; i < BINS; i++) { d1 -= s_lr[i]; d2 -= s_lc[i]; }
        out[0] = (float)(mi / fmin(d1, d2));
    }
}

extern "C" void kernel_launch(void* const* d_in, const int* in_sizes, int n_in,
                              void* d_out, int out_size, void* d_ws, size_t ws_size,
                              hipStream_t stream) {
    const float* e1 = (const float*)d_in[0];
    const float* e2 = (const float*)d_in[1];
    const float* dist = (const float*)d_in[2];
    const int B = in_sizes[2];
    unsigned* ws = (unsigned*)d_ws;

    k_init<<<(NHIST * NBINS2 + 255) / 256, 256, 0, stream>>>(ws);
    k_minmax<<<1024, 256, 0, stream>>>(dist, B, ws);
    k_simhist<<<GRID_SIMHIST, 256, 0, stream>>>(e1, e2, dist, B, ws);
    k_mi<<<1, 1024, 0, stream>>>(ws + 16, (float*)d_out);
}

// Round 6
// 289.146 us; speedup vs baseline: 1.1500x; 1.0251x over previous
//
#include <hip/hip_runtime.h>
#include <hip/hip_bf16.h>
#include <math.h>

#define BINS 100
#define NBINS2 (BINS * BINS)
#define NHIST 8                 // split global histograms to cut atomic contention
#define GRID_SIMHIST 2048       // rows/block <= 512 < 65535: 16-bit LDS counters safe

typedef float f32x4 __attribute__((ext_vector_type(4)));

static __device__ __forceinline__ f32x4 ntload(const f32x4* p) {
    return __builtin_nontemporal_load(p);
}

// wave-width-8 sum reduction, pure VALU (DPP), no DS pipe:
// xor1 = quad_perm(1,0,3,2)=0xB1, xor2 = quad_perm(2,3,0,1)=0x4E,
// cross-quad within 8 = row_half_mirror = 0x141
static __device__ __forceinline__ float red8(float v) {
    v += __int_as_float(__builtin_amdgcn_update_dpp(0, __float_as_int(v), 0xB1, 0xF, 0xF, true));
    v += __int_as_float(__builtin_amdgcn_update_dpp(0, __float_as_int(v), 0x4E, 0xF, 0xF, true));
    v += __int_as_float(__builtin_amdgcn_update_dpp(0, __float_as_int(v), 0x141, 0xF, 0xF, true));
    return v;
}

// ws layout (unsigned words):
//   ws[0] : monotone-encoded min of distances
//   ws[1] : monotone-encoded max of distances
//   ws[16 + h*NBINS2 + i], h=0..NHIST-1 : partial joint histograms (uint)

static __device__ __forceinline__ unsigned enc_f32(float f) {
    unsigned u = __float_as_uint(f);
    return (u & 0x80000000u) ? ~u : (u | 0x80000000u);
}
static __device__ __forceinline__ float dec_f32(unsigned e) {
    unsigned u = (e & 0x80000000u) ? (e & 0x7FFFFFFFu) : ~e;
    return __uint_as_float(u);
}

__global__ void k_init(unsigned* ws) {
    int i = blockIdx.x * blockDim.x + threadIdx.x;
    if (i == 0) { ws[0] = 0xFFFFFFFFu; ws[1] = 0u; }
    if (i < NHIST * NBINS2) ws[16 + i] = 0u;
}

__global__ __launch_bounds__(256) void k_minmax(const float* __restrict__ d, int n, unsigned* ws) {
    int tid = blockIdx.x * blockDim.x + threadIdx.x;
    int stride = gridDim.x * blockDim.x;
    float mn = INFINITY, mx = -INFINITY;
    int n4 = n >> 2;
    for (int i = tid; i < n4; i += stride) {
        float4 v = ((const float4*)d)[i];
        mn = fminf(mn, fminf(fminf(v.x, v.y), fminf(v.z, v.w)));
        mx = fmaxf(mx, fmaxf(fmaxf(v.x, v.y), fmaxf(v.z, v.w)));
    }
    int rem = n & 3;
    if (tid < rem) {
        float v = d[(n4 << 2) + tid];
        mn = fminf(mn, v);
        mx = fmaxf(mx, v);
    }
    #pragma unroll
    for (int off = 32; off; off >>= 1) {
        mn = fminf(mn, __shfl_xor(mn, off));
        mx = fmaxf(mx, __shfl_xor(mx, off));
    }
    if ((threadIdx.x & 63) == 0) {
        atomicMin(&ws[0], enc_f32(mn));
        atomicMax(&ws[1], enc_f32(mx));
    }
}

// searchsorted(edges, x, 'right') - 1: largest i with e[i] <= x < e[i+1].
static __device__ __forceinline__ int bin_fix(double x, const double* __restrict__ e, int guess) {
    int i = guess;
    if (i < 0) i = 0; else if (i > BINS - 1) i = BINS - 1;
    while (i >= 0 && x < e[i]) --i;           // -> -1 if x < e[0]
    while (i < BINS && x >= e[i + 1]) ++i;    // -> BINS if x >= e[BINS]
    return i;
}

struct GBuf {
    f32x4 a0, a1, a2, a3, b0, b1, b2, b3;
    float dv;
};

static __device__ __forceinline__ void g_load(
    GBuf& gb, const f32x4* __restrict__ e1, const f32x4* __restrict__ e2,
    const float* __restrict__ dist, int grp, int r, int s, int lane)
{
    size_t base = (size_t)grp * 256 + (size_t)(r * 32 + s);
    gb.a0 = ntload(e1 + base);      gb.a1 = ntload(e1 + base + 8);
    gb.a2 = ntload(e1 + base + 16); gb.a3 = ntload(e1 + base + 24);
    gb.b0 = ntload(e2 + base);      gb.b1 = ntload(e2 + base + 8);
    gb.b2 = ntload(e2 + base + 16); gb.b3 = ntload(e2 + base + 24);
    gb.dv = __builtin_nontemporal_load(dist + (grp << 3) + (lane >> 3));
}

static __device__ __forceinline__ void g_compute(
    const GBuf& gb, int grp, int r, int s,
    const double* __restrict__ s_se, const double* __restrict__ s_de,
    double dlo, double dinv, unsigned* s_hist)
{
    float dot = gb.a0.x*gb.b0.x + gb.a0.y*gb.b0.y + gb.a0.z*gb.b0.z + gb.a0.w*gb.b0.w
              + gb.a1.x*gb.b1.x + gb.a1.y*gb.b1.y + gb.a1.z*gb.b1.z + gb.a1.w*gb.b1.w
              + gb.a2.x*gb.b2.x + gb.a2.y*gb.b2.y + gb.a2.z*gb.b2.z + gb.a2.w*gb.b2.w
              + gb.a3.x*gb.b3.x + gb.a3.y*gb.b3.y + gb.a3.z*gb.b3.z + gb.a3.w*gb.b3.w;
    float n1  = gb.a0.x*gb.a0.x + gb.a0.y*gb.a0.y + gb.a0.z*gb.a0.z + gb.a0.w*gb.a0.w
              + gb.a1.x*gb.a1.x + gb.a1.y*gb.a1.y + gb.a1.z*gb.a1.z + gb.a1.w*gb.a1.w
              + gb.a2.x*gb.a2.x + gb.a2.y*gb.a2.y + gb.a2.z*gb.a2.z + gb.a2.w*gb.a2.w
              + gb.a3.x*gb.a3.x + gb.a3.y*gb.a3.y + gb.a3.z*gb.a3.z + gb.a3.w*gb.a3.w;
    float n2  = gb.b0.x*gb.b0.x + gb.b0.y*gb.b0.y + gb.b0.z*gb.b0.z + gb.b0.w*gb.b0.w
              + gb.b1.x*gb.b1.x + gb.b1.y*gb.b1.y + gb.b1.z*gb.b1.z + gb.b1.w*gb.b1.w
              + gb.b2.x*gb.b2.x + gb.b2.y*gb.b2.y + gb.b2.z*gb.b2.z + gb.b2.w*gb.b2.w
              + gb.b3.x*gb.b3.x + gb.b3.y*gb.b3.y + gb.b3.z*gb.b3.z + gb.b3.w*gb.b3.w;

    dot = red8(dot);
    n1 = red8(n1);
    n2 = red8(n2);

    if (s == 0) {
        float sim = dot / (fmaxf(sqrtf(n1), 1e-12f) * fmaxf(sqrtf(n2), 1e-12f));
        double xs = (double)sim;
        int is = bin_fix(xs, s_se, (int)floor((xs + 1.0) * 50.0));
        double xd = (double)gb.dv;
        int id = bin_fix(xd, s_de, (int)floor((xd - dlo) * dinv));
        if (is >= 0 && is < BINS && id >= 0 && id < BINS) {
            int bin = is * BINS + id;
            atomicAdd(&s_hist[bin >> 1], 1u << ((bin & 1) * 16));
        }
    }
}

// 8 rows (1 group) per wave-iteration, register double-buffered: while group k
// is reduced/binned, group k+1's 16 dwordx4 (+dist) are in flight. DPP-based
// 8-lane reduction keeps the compute window short (no DS pipe).
__global__ __launch_bounds__(256, 4) void k_simhist(
    const float* __restrict__ e1f, const float* __restrict__ e2f,
    const float* __restrict__ dist, int B, unsigned* ws)
{
    __shared__ unsigned s_hist[NBINS2 / 2];
    __shared__ double s_se[BINS + 1];
    __shared__ double s_de[BINS + 1];
    __shared__ double s_par[2];   // dist lo, dist inv_delta

    for (int i = threadIdx.x; i < NBINS2 / 2; i += 256) s_hist[i] = 0u;
    if (threadIdx.x <= BINS) {
        int i = threadIdx.x;
        s_se[i] = (i == BINS) ? 1.0 : ((double)i * 0.02 - 1.0);
        double dmn = (double)dec_f32(ws[0]);
        double dmx = (double)dec_f32(ws[1]);
        double delta = (dmx - dmn) * 0.01;
        s_de[i] = (i == BINS) ? dmx : ((double)i * delta + dmn);
        if (i == 0) {
            s_par[0] = dmn;
            s_par[1] = (delta > 0.0) ? (1.0 / delta) : 0.0;
        }
    }
    __syncthreads();

    const f32x4* __restrict__ e1 = (const f32x4*)e1f;
    const f32x4* __restrict__ e2 = (const f32x4*)e2f;
    const int lane = threadIdx.x & 63;
    const int r = lane >> 3, s = lane & 7;
    const int wid = (blockIdx.x * 256 + threadIdx.x) >> 6;
    const int nw = (gridDim.x * 256) >> 6;
    const int ngroups = B >> 3;
    const double dlo = s_par[0], dinv = s_par[1];

    GBuf A, B2;
    if (wid < ngroups) g_load(A, e1, e2, dist, wid, r, s, lane);
    for (int g = wid; g < ngroups; g += 2 * nw) {
        int gB = g + nw;
        if (gB < ngroups) g_load(B2, e1, e2, dist, gB, r, s, lane);
        g_compute(A, g, r, s, s_se, s_de, dlo, dinv, s_hist);
        if (gB < ngroups) {
            int gA2 = gB + nw;
            if (gA2 < ngroups) g_load(A, e1, e2, dist, gA2, r, s, lane);
            g_compute(B2, gB, r, s, s_se, s_de, dlo, dinv, s_hist);
        }
    }

    // tail rows (B % 8 != 0): block 0, wave 0, serial per row
    int tail = B & 7;
    if (tail && blockIdx.x == 0 && threadIdx.x < 64) {
        for (int row = B - tail; row < B; ++row) {
            const float* p1 = e1f + (size_t)row * 128;
            const float* p2 = e2f + (size_t)row * 128;
            float a0 = p1[lane * 2], a1 = p1[lane * 2 + 1];
            float b0 = p2[lane * 2], b1 = p2[lane * 2 + 1];
            float dot = a0 * b0 + a1 * b1;
            float n1 = a0 * a0 + a1 * a1;
            float n2 = b0 * b0 + b1 * b1;
            #pragma unroll
            for (int off = 32; off; off >>= 1) {
                dot += __shfl_xor(dot, off);
                n1 += __shfl_xor(n1, off);
                n2 += __shfl_xor(n2, off);
            }
            if (lane == 0) {
                float sim = dot / (fmaxf(sqrtf(n1), 1e-12f) * fmaxf(sqrtf(n2), 1e-12f));
                double xs = (double)sim;
                int is = bin_fix(xs, s_se, (int)floor((xs + 1.0) * 50.0));
                double xd = (double)dist[row];
                int id = bin_fix(xd, s_de, (int)floor((xd - dlo) * dinv));
                if (is >= 0 && is < BINS && id >= 0 && id < BINS) {
                    int bin = is * BINS + id;
                    atomicAdd(&s_hist[bin >> 1], 1u << ((bin & 1) * 16));
                }
            }
        }
    }

    __syncthreads();
    unsigned* g = ws + 16 + (blockIdx.x & (NHIST - 1)) * NBINS2;
    for (int i = threadIdx.x; i < NBINS2 / 2; i += 256) {
        unsigned c = s_hist[i];
        if (c & 0xFFFFu)  atomicAdd(&g[2 * i],     c & 0xFFFFu);
        if (c >> 16)      atomicAdd(&g[2 * i + 1], c >> 16);
    }
}

__global__ __launch_bounds__(1024) void k_mi(const unsigned* __restrict__ counts, float* __restrict__ out) {
    __shared__ unsigned s_c[NBINS2];
    __shared__ double s_red[1024];
    __shared__ double s_lr[BINS], s_lc[BINS];
    const int tid = threadIdx.x;

    double t = 0.0;
    for (int i = tid; i < NBINS2; i += 1024) {
        unsigned c = 0;
        #pragma unroll
        for (int h = 0; h < NHIST; ++h) c += counts[h * NBINS2 + i];
        s_c[i] = c;
        t += (double)c;
    }
    s_red[tid] = t;
    __syncthreads();
    for (int off = 512; off; off >>= 1) {
        if (tid < off) s_red[tid] += s_red[tid + off];
        __syncthreads();
    }
    double tot = s_red[0];
    __syncthreads();

    if (tid < 8 * BINS) {
        int r = tid >> 3, s = tid & 7;
        double rs = 0.0, cs = 0.0;
        for (int j = s; j < BINS; j += 8) {
            rs += (double)s_c[r * BINS + j];
            cs += (double)s_c[j * BINS + r];
        }
        rs += __shfl_xor(rs, 1); cs += __shfl_xor(cs, 1);
        rs += __shfl_xor(rs, 2); cs += __shfl_xor(cs, 2);
        rs += __shfl_xor(rs, 4); cs += __shfl_xor(cs, 4);
        if (s == 0) {
            s_lr[r] = log(rs / tot + 1e-10);
            s_lc[r] = log(cs / tot + 1e-10);
        }
    }
    __syncthreads();

    double acc = 0.0;
    for (int i = tid; i < NBINS2; i += 1024) {
        unsigned c = s_c[i];
        if (c) {
            double p = (double)c / tot;
            acc += p * (log(p + 1e-10) - s_lr[i / BINS] - s_lc[i % BINS]);
        }
    }
    s_red[tid] = acc;
    __syncthreads();
    for (int off = 512; off; off >>= 1) {
        if (tid < off) s_red[tid] += s_red[tid + off];
        __syncthreads();
    }
    if (tid == 0) {
        double mi = s_red[0];
        double d1 = 0.0, d2 = 0.0;
        for (int i = 0; i < BINS; i++) { d1 -= s_lr[i]; d2 -= s_lc[i]; }
        out[0] = (float)(mi / fmin(d1, d2));
    }
}

extern "C" void kernel_launch(void* const* d_in, const int* in_sizes, int n_in,
                              void* d_out, int out_size, void* d_ws, size_t ws_size,
                              hipStream_t stream) {
    const float* e1 = (const float*)d_in[0];
    const float* e2 = (const float*)d_in[1];
    const float* dist = (const float*)d_in[2];
    const int B = in_sizes[2];
    unsigned* ws = (unsigned*)d_ws;

    k_init<<<(NHIST * NBINS2 + 255) / 256, 256, 0, stream>>>(ws);
    k_minmax<<<1024, 256, 0, stream>>>(dist, B, ws);
    k_simhist<<<GRID_SIMHIST, 256, 0, stream>>>(e1, e2, dist, B, ws);
    k_mi<<<1, 1024, 0, stream>>>(ws + 16, (float*)d_out);
}

// Round 7
// 203.582 us; speedup vs baseline: 1.6334x; 1.4203x over previous
//
#include <hip/hip_runtime.h>
#include <hip/hip_bf16.h>
#include <math.h>

#define BINS 100
#define NBINS2 (BINS * BINS)
#define NHIST 8                 // split global histograms to cut atomic contention
#define GRID_SIMHIST 2048       // rows/block <= 512 < 65535: 16-bit LDS counters safe

typedef float f32x4 __attribute__((ext_vector_type(4)));

static __device__ __forceinline__ f32x4 ntload(const f32x4* p) {
    return __builtin_nontemporal_load(p);
}

// wave-width-8 sum reduction, pure VALU (DPP), no DS pipe.
static __device__ __forceinline__ float red8(float v) {
    v += __int_as_float(__builtin_amdgcn_update_dpp(0, __float_as_int(v), 0xB1, 0xF, 0xF, true));
    v += __int_as_float(__builtin_amdgcn_update_dpp(0, __float_as_int(v), 0x4E, 0xF, 0xF, true));
    v += __int_as_float(__builtin_amdgcn_update_dpp(0, __float_as_int(v), 0x141, 0xF, 0xF, true));
    return v;
}

// ws layout (unsigned words):
//   ws[0] : monotone-encoded min of distances
//   ws[1] : monotone-encoded max of distances
//   ws[16 + h*NBINS2 + i], h=0..NHIST-1 : partial joint histograms (uint)

static __device__ __forceinline__ unsigned enc_f32(float f) {
    unsigned u = __float_as_uint(f);
    return (u & 0x80000000u) ? ~u : (u | 0x80000000u);
}
static __device__ __forceinline__ float dec_f32(unsigned e) {
    unsigned u = (e & 0x80000000u) ? (e & 0x7FFFFFFFu) : ~e;
    return __uint_as_float(u);
}

__global__ void k_init(unsigned* ws) {
    int i = blockIdx.x * blockDim.x + threadIdx.x;
    if (i == 0) { ws[0] = 0xFFFFFFFFu; ws[1] = 0u; }
    if (i < NHIST * NBINS2) ws[16 + i] = 0u;
}

// 256 blocks; per-block LDS reduce -> ONE atomic pair per block (512 total).
__global__ __launch_bounds__(256) void k_minmax(const float* __restrict__ d, int n, unsigned* ws) {
    __shared__ float s_mn[4], s_mx[4];
    int tid = blockIdx.x * blockDim.x + threadIdx.x;
    int stride = gridDim.x * blockDim.x;
    float mn = INFINITY, mx = -INFINITY;
    int n4 = n >> 2;
    for (int i = tid; i < n4; i += stride) {
        float4 v = ((const float4*)d)[i];
        mn = fminf(mn, fminf(fminf(v.x, v.y), fminf(v.z, v.w)));
        mx = fmaxf(mx, fmaxf(fmaxf(v.x, v.y), fmaxf(v.z, v.w)));
    }
    int rem = n & 3;
    if (tid < rem) {
        float v = d[(n4 << 2) + tid];
        mn = fminf(mn, v);
        mx = fmaxf(mx, v);
    }
    #pragma unroll
    for (int off = 32; off; off >>= 1) {
        mn = fminf(mn, __shfl_xor(mn, off));
        mx = fmaxf(mx, __shfl_xor(mx, off));
    }
    int w = threadIdx.x >> 6;
    if ((threadIdx.x & 63) == 0) { s_mn[w] = mn; s_mx[w] = mx; }
    __syncthreads();
    if (threadIdx.x == 0) {
        mn = fminf(fminf(s_mn[0], s_mn[1]), fminf(s_mn[2], s_mn[3]));
        mx = fmaxf(fmaxf(s_mx[0], s_mx[1]), fmaxf(s_mx[2], s_mx[3]));
        atomicMin(&ws[0], enc_f32(mn));
        atomicMax(&ws[1], enc_f32(mx));
    }
}

// searchsorted(edges, x, 'right') - 1: largest i with e[i] <= x < e[i+1].
static __device__ __forceinline__ int bin_fix(double x, const double* __restrict__ e, int guess) {
    int i = guess;
    if (i < 0) i = 0; else if (i > BINS - 1) i = BINS - 1;
    while (i >= 0 && x < e[i]) --i;           // -> -1 if x < e[0]
    while (i < BINS && x >= e[i + 1]) ++i;    // -> BINS if x >= e[BINS]
    return i;
}

struct GBuf {
    f32x4 a0, a1, a2, a3, b0, b1, b2, b3;
    float dv;
};

static __device__ __forceinline__ void g_load(
    GBuf& gb, const f32x4* __restrict__ e1, const f32x4* __restrict__ e2,
    const float* __restrict__ dist, int grp, int r, int s, int lane)
{
    size_t base = (size_t)grp * 256 + (size_t)(r * 32 + s);
    gb.a0 = ntload(e1 + base);      gb.a1 = ntload(e1 + base + 8);
    gb.a2 = ntload(e1 + base + 16); gb.a3 = ntload(e1 + base + 24);
    gb.b0 = ntload(e2 + base);      gb.b1 = ntload(e2 + base + 8);
    gb.b2 = ntload(e2 + base + 16); gb.b3 = ntload(e2 + base + 24);
    gb.dv = __builtin_nontemporal_load(dist + (grp << 3) + (lane >> 3));
}

static __device__ __forceinline__ void g_compute(
    const GBuf& gb, int r, int s,
    const double* __restrict__ s_se, const double* __restrict__ s_de,
    double dlo, double dinv, unsigned* s_hist)
{
    float dot = gb.a0.x*gb.b0.x + gb.a0.y*gb.b0.y + gb.a0.z*gb.b0.z + gb.a0.w*gb.b0.w
              + gb.a1.x*gb.b1.x + gb.a1.y*gb.b1.y + gb.a1.z*gb.b1.z + gb.a1.w*gb.b1.w
              + gb.a2.x*gb.b2.x + gb.a2.y*gb.b2.y + gb.a2.z*gb.b2.z + gb.a2.w*gb.b2.w
              + gb.a3.x*gb.b3.x + gb.a3.y*gb.b3.y + gb.a3.z*gb.b3.z + gb.a3.w*gb.b3.w;
    float n1  = gb.a0.x*gb.a0.x + gb.a0.y*gb.a0.y + gb.a0.z*gb.a0.z + gb.a0.w*gb.a0.w
              + gb.a1.x*gb.a1.x + gb.a1.y*gb.a1.y + gb.a1.z*gb.a1.z + gb.a1.w*gb.a1.w
              + gb.a2.x*gb.a2.x + gb.a2.y*gb.a2.y + gb.a2.z*gb.a2.z + gb.a2.w*gb.a2.w
              + gb.a3.x*gb.a3.x + gb.a3.y*gb.a3.y + gb.a3.z*gb.a3.z + gb.a3.w*gb.a3.w;
    float n2  = gb.b0.x*gb.b0.x + gb.b0.y*gb.b0.y + gb.b0.z*gb.b0.z + gb.b0.w*gb.b0.w
              + gb.b1.x*gb.b1.x + gb.b1.y*gb.b1.y + gb.b1.z*gb.b1.z + gb.b1.w*gb.b1.w
              + gb.b2.x*gb.b2.x + gb.b2.y*gb.b2.y + gb.b2.z*gb.b2.z + gb.b2.w*gb.b2.w
              + gb.b3.x*gb.b3.x + gb.b3.y*gb.b3.y + gb.b3.z*gb.b3.z + gb.b3.w*gb.b3.w;

    dot = red8(dot);
    n1 = red8(n1);
    n2 = red8(n2);

    if (s == 0) {
        float sim = dot / (fmaxf(sqrtf(n1), 1e-12f) * fmaxf(sqrtf(n2), 1e-12f));
        double xs = (double)sim;
        int is = bin_fix(xs, s_se, (int)floor((xs + 1.0) * 50.0));
        double xd = (double)gb.dv;
        int id = bin_fix(xd, s_de, (int)floor((xd - dlo) * dinv));
        if (is >= 0 && is < BINS && id >= 0 && id < BINS) {
            int bin = is * BINS + id;
            atomicAdd(&s_hist[bin >> 1], 1u << ((bin & 1) * 16));
        }
    }
}

// 8 rows (1 group, 8 KB/wave) per stage; 3-deep register rotation: while group
// k is reduced/binned, groups k+1 and k+2 (16 KB) are in flight.
__global__ __launch_bounds__(256, 3) void k_simhist(
    const float* __restrict__ e1f, const float* __restrict__ e2f,
    const float* __restrict__ dist, int B, unsigned* ws)
{
    __shared__ unsigned s_hist[NBINS2 / 2];
    __shared__ double s_se[BINS + 1];
    __shared__ double s_de[BINS + 1];
    __shared__ double s_par[2];   // dist lo, dist inv_delta

    for (int i = threadIdx.x; i < NBINS2 / 2; i += 256) s_hist[i] = 0u;
    if (threadIdx.x <= BINS) {
        int i = threadIdx.x;
        s_se[i] = (i == BINS) ? 1.0 : ((double)i * 0.02 - 1.0);
        double dmn = (double)dec_f32(ws[0]);
        double dmx = (double)dec_f32(ws[1]);
        double delta = (dmx - dmn) * 0.01;
        s_de[i] = (i == BINS) ? dmx : ((double)i * delta + dmn);
        if (i == 0) {
            s_par[0] = dmn;
            s_par[1] = (delta > 0.0) ? (1.0 / delta) : 0.0;
        }
    }
    __syncthreads();

    const f32x4* __restrict__ e1 = (const f32x4*)e1f;
    const f32x4* __restrict__ e2 = (const f32x4*)e2f;
    const int lane = threadIdx.x & 63;
    const int r = lane >> 3, s = lane & 7;
    const int wid = (blockIdx.x * 256 + threadIdx.x) >> 6;
    const int nw = (gridDim.x * 256) >> 6;
    const int ngroups = B >> 3;
    const double dlo = s_par[0], dinv = s_par[1];

    GBuf A, Bb, C;
    if (wid < ngroups)          g_load(A,  e1, e2, dist, wid,          r, s, lane);
    if (wid + nw < ngroups)     g_load(Bb, e1, e2, dist, wid + nw,     r, s, lane);

    for (int g = wid; g < ngroups; g += 3 * nw) {
        // stage A: compute g, prefetch g+2nw
        if (g + 2 * nw < ngroups) g_load(C, e1, e2, dist, g + 2 * nw, r, s, lane);
        g_compute(A, r, s, s_se, s_de, dlo, dinv, s_hist);
        // stage B: compute g+nw, prefetch g+3nw
        if (g + nw < ngroups) {
            if (g + 3 * nw < ngroups) g_load(A, e1, e2, dist, g + 3 * nw, r, s, lane);
            g_compute(Bb, r, s, s_se, s_de, dlo, dinv, s_hist);
        }
        // stage C: compute g+2nw, prefetch g+4nw
        if (g + 2 * nw < ngroups) {
            if (g + 4 * nw < ngroups) g_load(Bb, e1, e2, dist, g + 4 * nw, r, s, lane);
            g_compute(C, r, s, s_se, s_de, dlo, dinv, s_hist);
        }
    }

    // tail rows (B % 8 != 0): block 0, wave 0, serial per row
    int tail = B & 7;
    if (tail && blockIdx.x == 0 && threadIdx.x < 64) {
        for (int row = B - tail; row < B; ++row) {
            const float* p1 = e1f + (size_t)row * 128;
            const float* p2 = e2f + (size_t)row * 128;
            float a0 = p1[lane * 2], a1 = p1[lane * 2 + 1];
            float b0 = p2[lane * 2], b1 = p2[lane * 2 + 1];
            float dot = a0 * b0 + a1 * b1;
            float n1 = a0 * a0 + a1 * a1;
            float n2 = b0 * b0 + b1 * b1;
            #pragma unroll
            for (int off = 32; off; off >>= 1) {
                dot += __shfl_xor(dot, off);
                n1 += __shfl_xor(n1, off);
                n2 += __shfl_xor(n2, off);
            }
            if (lane == 0) {
                float sim = dot / (fmaxf(sqrtf(n1), 1e-12f) * fmaxf(sqrtf(n2), 1e-12f));
                double xs = (double)sim;
                int is = bin_fix(xs, s_se, (int)floor((xs + 1.0) * 50.0));
                double xd = (double)dist[row];
                int id = bin_fix(xd, s_de, (int)floor((xd - dlo) * dinv));
                if (is >= 0 && is < BINS && id >= 0 && id < BINS) {
                    int bin = is * BINS + id;
                    atomicAdd(&s_hist[bin >> 1], 1u << ((bin & 1) * 16));
                }
            }
        }
    }

    __syncthreads();
    unsigned* gh = ws + 16 + (blockIdx.x & (NHIST - 1)) * NBINS2;
    for (int i = threadIdx.x; i < NBINS2 / 2; i += 256) {
        unsigned c = s_hist[i];
        if (c & 0xFFFFu)  atomicAdd(&gh[2 * i],     c & 0xFFFFu);
        if (c >> 16)      atomicAdd(&gh[2 * i + 1], c >> 16);
    }
}

__global__ __launch_bounds__(1024) void k_mi(const unsigned* __restrict__ counts, float* __restrict__ out) {
    __shared__ unsigned s_c[NBINS2];
    __shared__ double s_red[1024];
    __shared__ double s_lr[BINS], s_lc[BINS];
    const int tid = threadIdx.x;

    double t = 0.0;
    for (int i = tid; i < NBINS2; i += 1024) {
        unsigned c = 0;
        #pragma unroll
        for (int h = 0; h < NHIST; ++h) c += counts[h * NBINS2 + i];
        s_c[i] = c;
        t += (double)c;
    }
    s_red[tid] = t;
    __syncthreads();
    for (int off = 512; off; off >>= 1) {
        if (tid < off) s_red[tid] += s_red[tid + off];
        __syncthreads();
    }
    double tot = s_red[0];
    __syncthreads();

    if (tid < 8 * BINS) {
        int r = tid >> 3, s = tid & 7;
        double rs = 0.0, cs = 0.0;
        for (int j = s; j < BINS; j += 8) {
            rs += (double)s_c[r * BINS + j];
            cs += (double)s_c[j * BINS + r];
        }
        rs += __shfl_xor(rs, 1); cs += __shfl_xor(cs, 1);
        rs += __shfl_xor(rs, 2); cs += __shfl_xor(cs, 2);
        rs += __shfl_xor(rs, 4); cs += __shfl_xor(cs, 4);
        if (s == 0) {
            s_lr[r] = log(rs / tot + 1e-10);
            s_lc[r] = log(cs / tot + 1e-10);
        }
    }
    __syncthreads();

    double acc = 0.0;
    for (int i = tid; i < NBINS2; i += 1024) {
        unsigned c = s_c[i];
        if (c) {
            double p = (double)c / tot;
            acc += p * (log(p + 1e-10) - s_lr[i / BINS] - s_lc[i % BINS]);
        }
    }
    s_red[tid] = acc;
    __syncthreads();
    for (int off = 512; off; off >>= 1) {
        if (tid < off) s_red[tid] += s_red[tid + off];
        __syncthreads();
    }
    if (tid == 0) {
        double mi = s_red[0];
        double d1 = 0.0, d2 = 0.0;
        for (int i = 0; i < BINS; i++) { d1 -= s_lr[i]; d2 -= s_lc[i]; }
        out[0] = (float)(mi / fmin(d1, d2));
    }
}

extern "C" void kernel_launch(void* const* d_in, const int* in_sizes, int n_in,
                              void* d_out, int out_size, void* d_ws, size_t ws_size,
                              hipStream_t stream) {
    const float* e1 = (const float*)d_in[0];
    const float* e2 = (const float*)d_in[1];
    const float* dist = (const float*)d_in[2];
    const int B = in_sizes[2];
    unsigned* ws = (unsigned*)d_ws;

    k_init<<<(NHIST * NBINS2 + 255) / 256, 256, 0, stream>>>(ws);
    k_minmax<<<256, 256, 0, stream>>>(dist, B, ws);
    k_simhist<<<GRID_SIMHIST, 256, 0, stream>>>(e1, e2, dist, B, ws);
    k_mi<<<1, 1024, 0, stream>>>(ws + 16, (float*)d_out);
}

// Round 8
// 198.246 us; speedup vs baseline: 1.6773x; 1.0269x over previous
//
#include <hip/hip_runtime.h>
#include <hip/hip_bf16.h>
#include <math.h>

#define BINS 100
#define NBINS2 (BINS * BINS)
#define NHIST 8                 // split global histograms to cut atomic contention
#define GRID_SIMHIST 2048       // rows/block <= 512 < 65535: 16-bit LDS counters safe

typedef float f32x4 __attribute__((ext_vector_type(4)));

static __device__ __forceinline__ f32x4 ntload(const f32x4* p) {
    return __builtin_nontemporal_load(p);
}

// wave-width-8 sum reduction, pure VALU (DPP), no DS pipe.
static __device__ __forceinline__ float red8(float v) {
    v += __int_as_float(__builtin_amdgcn_update_dpp(0, __float_as_int(v), 0xB1, 0xF, 0xF, true));
    v += __int_as_float(__builtin_amdgcn_update_dpp(0, __float_as_int(v), 0x4E, 0xF, 0xF, true));
    v += __int_as_float(__builtin_amdgcn_update_dpp(0, __float_as_int(v), 0x141, 0xF, 0xF, true));
    return v;
}

// ws layout (unsigned words):
//   ws[0] : monotone-encoded min of distances
//   ws[1] : monotone-encoded max of distances
//   ws[16 + h*NBINS2 + i], h=0..NHIST-1 : partial joint histograms (uint)

static __device__ __forceinline__ unsigned enc_f32(float f) {
    unsigned u = __float_as_uint(f);
    return (u & 0x80000000u) ? ~u : (u | 0x80000000u);
}
static __device__ __forceinline__ float dec_f32(unsigned e) {
    unsigned u = (e & 0x80000000u) ? (e & 0x7FFFFFFFu) : ~e;
    return __uint_as_float(u);
}

// Fused: zero the NHIST histograms + seed min/max slots + dist min/max scan.
// One atomic pair per block (256 blocks).
__global__ __launch_bounds__(256) void k_initminmax(const float* __restrict__ d, int n, unsigned* ws) {
    __shared__ float s_mn[4], s_mx[4];
    int tid = blockIdx.x * blockDim.x + threadIdx.x;
    int stride = gridDim.x * blockDim.x;

    if (tid == 0) { ws[0] = 0xFFFFFFFFu; ws[1] = 0u; }
    for (int i = tid; i < NHIST * NBINS2; i += stride) ws[16 + i] = 0u;

    float mn = INFINITY, mx = -INFINITY;
    int n4 = n >> 2;
    for (int i = tid; i < n4; i += stride) {
        float4 v = ((const float4*)d)[i];
        mn = fminf(mn, fminf(fminf(v.x, v.y), fminf(v.z, v.w)));
        mx = fmaxf(mx, fmaxf(fmaxf(v.x, v.y), fmaxf(v.z, v.w)));
    }
    int rem = n & 3;
    if (tid < rem) {
        float v = d[(n4 << 2) + tid];
        mn = fminf(mn, v);
        mx = fmaxf(mx, v);
    }
    #pragma unroll
    for (int off = 32; off; off >>= 1) {
        mn = fminf(mn, __shfl_xor(mn, off));
        mx = fmaxf(mx, __shfl_xor(mx, off));
    }
    int w = threadIdx.x >> 6;
    if ((threadIdx.x & 63) == 0) { s_mn[w] = mn; s_mx[w] = mx; }
    __syncthreads();
    if (threadIdx.x == 0) {
        mn = fminf(fminf(s_mn[0], s_mn[1]), fminf(s_mn[2], s_mn[3]));
        mx = fmaxf(fmaxf(s_mx[0], s_mx[1]), fmaxf(s_mx[2], s_mx[3]));
        atomicMin(&ws[0], enc_f32(mn));
        atomicMax(&ws[1], enc_f32(mx));
    }
}

// searchsorted(edges, x, 'right') - 1: largest i with e[i] <= x < e[i+1].
static __device__ __forceinline__ int bin_fix(double x, const double* __restrict__ e, int guess) {
    int i = guess;
    if (i < 0) i = 0; else if (i > BINS - 1) i = BINS - 1;
    while (i >= 0 && x < e[i]) --i;           // -> -1 if x < e[0]
    while (i < BINS && x >= e[i + 1]) ++i;    // -> BINS if x >= e[BINS]
    return i;
}

struct GBuf {
    f32x4 a0, a1, a2, a3, b0, b1, b2, b3;
    float dv;
};

static __device__ __forceinline__ void g_load(
    GBuf& gb, const f32x4* __restrict__ e1, const f32x4* __restrict__ e2,
    const float* __restrict__ dist, int grp, int r, int s, int lane)
{
    size_t base = (size_t)grp * 256 + (size_t)(r * 32 + s);
    gb.a0 = ntload(e1 + base);      gb.a1 = ntload(e1 + base + 8);
    gb.a2 = ntload(e1 + base + 16); gb.a3 = ntload(e1 + base + 24);
    gb.b0 = ntload(e2 + base);      gb.b1 = ntload(e2 + base + 8);
    gb.b2 = ntload(e2 + base + 16); gb.b3 = ntload(e2 + base + 24);
    gb.dv = __builtin_nontemporal_load(dist + (grp << 3) + (lane >> 3));
}

static __device__ __forceinline__ void g_compute(
    const GBuf& gb, int r, int s,
    const double* __restrict__ s_se, const double* __restrict__ s_de,
    double dlo, double dinv, unsigned* s_hist)
{
    float dot = gb.a0.x*gb.b0.x + gb.a0.y*gb.b0.y + gb.a0.z*gb.b0.z + gb.a0.w*gb.b0.w
              + gb.a1.x*gb.b1.x + gb.a1.y*gb.b1.y + gb.a1.z*gb.b1.z + gb.a1.w*gb.b1.w
              + gb.a2.x*gb.b2.x + gb.a2.y*gb.b2.y + gb.a2.z*gb.b2.z + gb.a2.w*gb.b2.w
              + gb.a3.x*gb.b3.x + gb.a3.y*gb.b3.y + gb.a3.z*gb.b3.z + gb.a3.w*gb.b3.w;
    float n1  = gb.a0.x*gb.a0.x + gb.a0.y*gb.a0.y + gb.a0.z*gb.a0.z + gb.a0.w*gb.a0.w
              + gb.a1.x*gb.a1.x + gb.a1.y*gb.a1.y + gb.a1.z*gb.a1.z + gb.a1.w*gb.a1.w
              + gb.a2.x*gb.a2.x + gb.a2.y*gb.a2.y + gb.a2.z*gb.a2.z + gb.a2.w*gb.a2.w
              + gb.a3.x*gb.a3.x + gb.a3.y*gb.a3.y + gb.a3.z*gb.a3.z + gb.a3.w*gb.a3.w;
    float n2  = gb.b0.x*gb.b0.x + gb.b0.y*gb.b0.y + gb.b0.z*gb.b0.z + gb.b0.w*gb.b0.w
              + gb.b1.x*gb.b1.x + gb.b1.y*gb.b1.y + gb.b1.z*gb.b1.z + gb.b1.w*gb.b1.w
              + gb.b2.x*gb.b2.x + gb.b2.y*gb.b2.y + gb.b2.z*gb.b2.z + gb.b2.w*gb.b2.w
              + gb.b3.x*gb.b3.x + gb.b3.y*gb.b3.y + gb.b3.z*gb.b3.z + gb.b3.w*gb.b3.w;

    dot = red8(dot);
    n1 = red8(n1);
    n2 = red8(n2);

    if (s == 0) {
        float sim = dot / (fmaxf(sqrtf(n1), 1e-12f) * fmaxf(sqrtf(n2), 1e-12f));
        double xs = (double)sim;
        int is = bin_fix(xs, s_se, (int)floor((xs + 1.0) * 50.0));
        double xd = (double)gb.dv;
        int id = bin_fix(xd, s_de, (int)floor((xd - dlo) * dinv));
        if (is >= 0 && is < BINS && id >= 0 && id < BINS) {
            int bin = is * BINS + id;
            atomicAdd(&s_hist[bin >> 1], 1u << ((bin & 1) * 16));
        }
    }
}

// 8 rows (1 group, 8 KB/wave) per stage; 4-deep register rotation: while group
// k is reduced/binned, groups k+1..k+3 (24 KB/wave) are in flight.
__global__ __launch_bounds__(256, 3) void k_simhist(
    const float* __restrict__ e1f, const float* __restrict__ e2f,
    const float* __restrict__ dist, int B, unsigned* ws)
{
    __shared__ unsigned s_hist[NBINS2 / 2];
    __shared__ double s_se[BINS + 1];
    __shared__ double s_de[BINS + 1];
    __shared__ double s_par[2];   // dist lo, dist inv_delta

    for (int i = threadIdx.x; i < NBINS2 / 2; i += 256) s_hist[i] = 0u;
    if (threadIdx.x <= BINS) {
        int i = threadIdx.x;
        s_se[i] = (i == BINS) ? 1.0 : ((double)i * 0.02 - 1.0);
        double dmn = (double)dec_f32(ws[0]);
        double dmx = (double)dec_f32(ws[1]);
        double delta = (dmx - dmn) * 0.01;
        s_de[i] = (i == BINS) ? dmx : ((double)i * delta + dmn);
        if (i == 0) {
            s_par[0] = dmn;
            s_par[1] = (delta > 0.0) ? (1.0 / delta) : 0.0;
        }
    }
    __syncthreads();

    const f32x4* __restrict__ e1 = (const f32x4*)e1f;
    const f32x4* __restrict__ e2 = (const f32x4*)e2f;
    const int lane = threadIdx.x & 63;
    const int r = lane >> 3, s = lane & 7;
    const int wid = (blockIdx.x * 256 + threadIdx.x) >> 6;
    const int nw = (gridDim.x * 256) >> 6;
    const int ngroups = B >> 3;
    const double dlo = s_par[0], dinv = s_par[1];

    GBuf A, Bb, C, D;
    if (wid < ngroups)           g_load(A,  e1, e2, dist, wid,           r, s, lane);
    if (wid + nw < ngroups)      g_load(Bb, e1, e2, dist, wid + nw,      r, s, lane);
    if (wid + 2 * nw < ngroups)  g_load(C,  e1, e2, dist, wid + 2 * nw,  r, s, lane);

    for (int g = wid; g < ngroups; g += 4 * nw) {
        // stage 0: compute g, prefetch g+3nw
        if (g + 3 * nw < ngroups) g_load(D, e1, e2, dist, g + 3 * nw, r, s, lane);
        g_compute(A, r, s, s_se, s_de, dlo, dinv, s_hist);
        // stage 1: compute g+nw, prefetch g+4nw
        if (g + nw < ngroups) {
            if (g + 4 * nw < ngroups) g_load(A, e1, e2, dist, g + 4 * nw, r, s, lane);
            g_compute(Bb, r, s, s_se, s_de, dlo, dinv, s_hist);
        }
        // stage 2: compute g+2nw, prefetch g+5nw
        if (g + 2 * nw < ngroups) {
            if (g + 5 * nw < ngroups) g_load(Bb, e1, e2, dist, g + 5 * nw, r, s, lane);
            g_compute(C, r, s, s_se, s_de, dlo, dinv, s_hist);
        }
        // stage 3: compute g+3nw, prefetch g+6nw
        if (g + 3 * nw < ngroups) {
            if (g + 6 * nw < ngroups) g_load(C, e1, e2, dist, g + 6 * nw, r, s, lane);
            g_compute(D, r, s, s_se, s_de, dlo, dinv, s_hist);
        }
    }

    // tail rows (B % 8 != 0): block 0, wave 0, serial per row
    int tail = B & 7;
    if (tail && blockIdx.x == 0 && threadIdx.x < 64) {
        for (int row = B - tail; row < B; ++row) {
            const float* p1 = e1f + (size_t)row * 128;
            const float* p2 = e2f + (size_t)row * 128;
            float a0 = p1[lane * 2], a1 = p1[lane * 2 + 1];
            float b0 = p2[lane * 2], b1 = p2[lane * 2 + 1];
            float dot = a0 * b0 + a1 * b1;
            float n1 = a0 * a0 + a1 * a1;
            float n2 = b0 * b0 + b1 * b1;
            #pragma unroll
            for (int off = 32; off; off >>= 1) {
                dot += __shfl_xor(dot, off);
                n1 += __shfl_xor(n1, off);
                n2 += __shfl_xor(n2, off);
            }
            if (lane == 0) {
                float sim = dot / (fmaxf(sqrtf(n1), 1e-12f) * fmaxf(sqrtf(n2), 1e-12f));
                double xs = (double)sim;
                int is = bin_fix(xs, s_se, (int)floor((xs + 1.0) * 50.0));
                double xd = (double)dist[row];
                int id = bin_fix(xd, s_de, (int)floor((xd - dlo) * dinv));
                if (is >= 0 && is < BINS && id >= 0 && id < BINS) {
                    int bin = is * BINS + id;
                    atomicAdd(&s_hist[bin >> 1], 1u << ((bin & 1) * 16));
                }
            }
        }
    }

    __syncthreads();
    unsigned* gh = ws + 16 + (blockIdx.x & (NHIST - 1)) * NBINS2;
    for (int i = threadIdx.x; i < NBINS2 / 2; i += 256) {
        unsigned c = s_hist[i];
        if (c & 0xFFFFu)  atomicAdd(&gh[2 * i],     c & 0xFFFFu);
        if (c >> 16)      atomicAdd(&gh[2 * i + 1], c >> 16);
    }
}

__global__ __launch_bounds__(1024) void k_mi(const unsigned* __restrict__ counts, float* __restrict__ out) {
    __shared__ unsigned s_c[NBINS2];
    __shared__ double s_red[1024];
    __shared__ double s_lr[BINS], s_lc[BINS];
    const int tid = threadIdx.x;

    double t = 0.0;
    for (int i = tid; i < NBINS2; i += 1024) {
        unsigned c = 0;
        #pragma unroll
        for (int h = 0; h < NHIST; ++h) c += counts[h * NBINS2 + i];
        s_c[i] = c;
        t += (double)c;
    }
    s_red[tid] = t;
    __syncthreads();
    for (int off = 512; off; off >>= 1) {
        if (tid < off) s_red[tid] += s_red[tid + off];
        __syncthreads();
    }
    double tot = s_red[0];
    __syncthreads();

    if (tid < 8 * BINS) {
        int r = tid >> 3, s = tid & 7;
        double rs = 0.0, cs = 0.0;
        for (int j = s; j < BINS; j += 8) {
            rs += (double)s_c[r * BINS + j];
            cs += (double)s_c[j * BINS + r];
        }
        rs += __shfl_xor(rs, 1); cs += __shfl_xor(cs, 1);
        rs += __shfl_xor(rs, 2); cs += __shfl_xor(cs, 2);
        rs += __shfl_xor(rs, 4); cs += __shfl_xor(cs, 4);
        if (s == 0) {
            s_lr[r] = log(rs / tot + 1e-10);
            s_lc[r] = log(cs / tot + 1e-10);
        }
    }
    __syncthreads();

    double acc = 0.0;
    for (int i = tid; i < NBINS2; i += 1024) {
        unsigned c = s_c[i];
        if (c) {
            double p = (double)c / tot;
            acc += p * (log(p + 1e-10) - s_lr[i / BINS] - s_lc[i % BINS]);
        }
    }
    s_red[tid] = acc;
    __syncthreads();
    for (int off = 512; off; off >>= 1) {
        if (tid < off) s_red[tid] += s_red[tid + off];
        __syncthreads();
    }
    if (tid == 0) {
        double mi = s_red[0];
        double d1 = 0.0, d2 = 0.0;
        for (int i = 0; i < BINS; i++) { d1 -= s_lr[i]; d2 -= s_lc[i]; }
        out[0] = (float)(mi / fmin(d1, d2));
    }
}

extern "C" void kernel_launch(void* const* d_in, const int* in_sizes, int n_in,
                              void* d_out, int out_size, void* d_ws, size_t ws_size,
                              hipStream_t stream) {
    const float* e1 = (const float*)d_in[0];
    const float* e2 = (const float*)d_in[1];
    const float* dist = (const float*)d_in[2];
    const int B = in_sizes[2];
    unsigned* ws = (unsigned*)d_ws;

    k_initminmax<<<256, 256, 0, stream>>>(dist, B, ws);
    k_simhist<<<GRID_SIMHIST, 256, 0, stream>>>(e1, e2, dist, B, ws);
    k_mi<<<1, 1024, 0, stream>>>(ws + 16, (float*)d_out);
}